// Round 9
// baseline (119.808 us; speedup 1.0000x reference)
//
#include <hip/hip_runtime.h>

#define AS_GLOBAL __attribute__((address_space(1)))
#define AS_LDS    __attribute__((address_space(3)))

typedef __bf16 bf16;
typedef __bf16 bf16x4 __attribute__((ext_vector_type(4)));
typedef __bf16 bf16x8 __attribute__((ext_vector_type(8)));
typedef float  f32x4  __attribute__((ext_vector_type(4)));
typedef unsigned short u16x8 __attribute__((ext_vector_type(8)));

__device__ __forceinline__ void gload16(const void* g, void* l) {
  __builtin_amdgcn_global_load_lds((const AS_GLOBAL unsigned int*)g,
                                   (AS_LDS unsigned int*)l, 16, 0, 0);
}

// swizzled LDS address for a [R][128B] row-major tile:
// stored_byte = row*128 + (bytecol ^ ((row&7)<<4))
__device__ __forceinline__ void* swz(void* base, int row, int bytecol) {
  return (char*)base + row * 128 + (bytecol ^ ((row & 7) << 4));
}

// compacted-column helpers: kept columns are s with !(s%3==1 && s>=4).
__device__ __forceinline__ int keptcnt(int X) { return X - ((X - 2) < 0 ? 0 : (X - 2) / 3); }
__device__ __forceinline__ int ci2s(int ci) {
  return 3 * ((ci - 2) >> 1) + 2 + ((ci - 2) & 1);
}
__device__ __forceinline__ int ci2s_full(int ci) {
  return ci < 2 ? ci : ci2s(ci);
}

// ---------------- prep kernels ----------------

__global__ __launch_bounds__(256) void k_cvt_bf16(const float* __restrict__ x,
                                                  bf16* __restrict__ o, int n8) {
  int i = blockIdx.x * blockDim.x + threadIdx.x;
  if (i >= n8) return;
  const float4* p = (const float4*)(x + (size_t)i * 8);
  float4 a = p[0], b = p[1];
  bf16x8 v;
  v[0] = (bf16)a.x; v[1] = (bf16)a.y; v[2] = (bf16)a.z; v[3] = (bf16)a.w;
  v[4] = (bf16)b.x; v[5] = (bf16)b.y; v[6] = (bf16)b.z; v[7] = (bf16)b.w;
  *(bf16x8*)(o + (size_t)i * 8) = v;
}

// W [K=1024][N=1024] fp32 (in,out) -> WT [N][K] bf16
__global__ __launch_bounds__(256) void k_wt(const float* __restrict__ W,
                                            bf16* __restrict__ WT) {
  int lin = blockIdx.x * blockDim.x + threadIdx.x;
  int n  = lin & 1023;
  int kc = lin >> 10;
  bf16x8 v;
#pragma unroll
  for (int j = 0; j < 8; ++j) v[j] = (bf16)W[(size_t)(kc * 8 + j) * 1024 + n];
  *(bf16x8*)&WT[(size_t)n * 1024 + kc * 8] = v;
}

__global__ __launch_bounds__(256) void k_bcat(const float* __restrict__ bq,
                                              const float* __restrict__ bk,
                                              const float* __restrict__ bv,
                                              float* __restrict__ bc) {
  int i = blockIdx.x * blockDim.x + threadIdx.x;
  if (i < 1024) bc[i] = bq[i];
  else if (i < 2048) bc[i] = bk[i - 1024];
  else if (i < 3072) bc[i] = bv[i - 2048];
}

// K rows gathered by compact index: Kc[bh][1408][64]; zero-fill padding.
__global__ __launch_bounds__(256) void k_compact_k(const bf16* __restrict__ qkv,
                                                   bf16* __restrict__ kc) {
  int blk = blockIdx.x;                 // 32 bh * 44 rowchunks = 1408
  int bh = blk / 44, rc = blk % 44;
  int b = bh >> 4, h = bh & 15;
  int rr = threadIdx.x >> 3, ch = threadIdx.x & 7;
  int ci = rc * 32 + rr;
  int s = ci2s_full(ci);
  bf16x8 v = {};
  if (s < 2048)
    v = *(const bf16x8*)&qkv[(size_t)(b * 2048 + s) * 3072 + 1024 + h * 64 + ch * 8];
  *(bf16x8*)&kc[((size_t)bh * 1408 + ci) * 64 + ch * 8] = v;
}

// V gathered + transposed: Vc[bh][64][1408]; u32-packed LDS transpose.
__global__ __launch_bounds__(256) void k_compact_v(const bf16* __restrict__ qkv,
                                                   bf16* __restrict__ vc) {
  __shared__ unsigned L[32 * 65];
  int blk = blockIdx.x;                 // 32 bh * 22 cichunks = 704
  int bh = blk / 22, cc = blk % 22;
  int b = bh >> 4, h = bh & 15;
  int ci0 = cc * 64;
  int tid = threadIdx.x;
  int p = tid >> 3, d0 = (tid & 7) * 8;
  int s0 = ci2s_full(ci0 + 2 * p), s1 = ci2s_full(ci0 + 2 * p + 1);
  u16x8 e = {}, od = {};
  if (s0 < 2048)
    e = *(const u16x8*)&qkv[(size_t)(b * 2048 + s0) * 3072 + 2048 + h * 64 + d0];
  if (s1 < 2048)
    od = *(const u16x8*)&qkv[(size_t)(b * 2048 + s1) * 3072 + 2048 + h * 64 + d0];
#pragma unroll
  for (int k2 = 0; k2 < 8; ++k2)
    L[p * 65 + d0 + k2] = (unsigned)e[k2] | ((unsigned)od[k2] << 16);
  __syncthreads();
#pragma unroll
  for (int it = 0; it < 2; ++it) {
    int d = it * 32 + (tid >> 3), jg = tid & 7;
    unsigned q4[4];
#pragma unroll
    for (int jj = 0; jj < 4; ++jj) q4[jj] = L[(jg * 4 + jj) * 65 + d];
    *(uint4*)&vc[((size_t)bh * 64 + d) * 1408 + ci0 + jg * 8] = *(uint4*)q4;
  }
}

// ---------------- 128^2 GEMM (kept for the output projection) -------------
template <typename OutT>
__global__ __launch_bounds__(256) void k_gemm_bt(const bf16* __restrict__ A,
                                                 const bf16* __restrict__ Bt,
                                                 const float* __restrict__ bias,
                                                 OutT* __restrict__ C,
                                                 int K, int N) {
  __shared__ bf16 As[2][128 * 32];
  __shared__ bf16 Bs[2][128 * 32];
  const int tid = threadIdx.x;
  const int w = tid >> 6, l = tid & 63, g = l >> 4, c = l & 15;
  const int wr = w >> 1, wc = w & 1;
  int lin = blockIdx.y * gridDim.x + blockIdx.x;
  int chunk = (gridDim.x * gridDim.y) >> 3;
  int nl = (lin & 7) * chunk + (lin >> 3);
  const int row0 = (nl % gridDim.x) * 128, col0 = (nl / gridDim.x) * 128;
  f32x4 acc[4][4] = {};

  auto stage = [&](int buf, int k0) {
#pragma unroll
    for (int it = 0; it < 2; ++it) {
      int idx = it * 256 + tid;
      int r = idx >> 2, cc = idx & 3;
      int jj = cc ^ ((r >> 1) & 3);
      gload16(A  + (size_t)(row0 + r) * K + k0 + jj * 8, &As[buf][idx * 8]);
      gload16(Bt + (size_t)(col0 + r) * K + k0 + jj * 8, &Bs[buf][idx * 8]);
    }
  };

  stage(0, 0);
  int cur = 0;
#pragma unroll 1
  for (int k0 = 0; k0 < K; k0 += 32) {
    asm volatile("s_waitcnt vmcnt(0)" ::: "memory");
    __builtin_amdgcn_sched_barrier(0);
    __builtin_amdgcn_s_barrier();
    __builtin_amdgcn_sched_barrier(0);

    if (k0 + 32 < K) stage(cur ^ 1, k0 + 32);

    bf16x8 af[4], bfr[4];
#pragma unroll
    for (int m = 0; m < 4; ++m) {
      int row = wr * 64 + m * 16 + c;
      af[m] = *(const bf16x8*)&As[cur][row * 32 + (g ^ ((row >> 1) & 3)) * 8];
    }
#pragma unroll
    for (int n = 0; n < 4; ++n) {
      int row = wc * 64 + n * 16 + c;
      bfr[n] = *(const bf16x8*)&Bs[cur][row * 32 + (g ^ ((row >> 1) & 3)) * 8];
    }
#pragma unroll
    for (int m = 0; m < 4; ++m)
#pragma unroll
      for (int n = 0; n < 4; ++n)
        acc[m][n] = __builtin_amdgcn_mfma_f32_16x16x32_bf16(af[m], bfr[n],
                                                            acc[m][n], 0, 0, 0);
    cur ^= 1;
  }

#pragma unroll
  for (int m = 0; m < 4; ++m) {
    int row = row0 + wr * 64 + m * 16 + g * 4;
#pragma unroll
    for (int n = 0; n < 4; ++n) {
      int col = col0 + wc * 64 + n * 16 + c;
      float bv = bias[col];
#pragma unroll
      for (int r = 0; r < 4; ++r) {
        float v = acc[m][n][r] + bv;
        C[(size_t)(row + r) * N + col] = (OutT)v;
      }
    }
  }
}

// ---------------- 256^2 8-phase GEMM (QKV) --------------------------------
// 512 thr = 8 waves (2M x 4N); per-wave C = 128x64 (8 m-frags x 4 n-frags).
// BK=64, 2 LDS buffers (128KB). Per K-tile: 4 phases, each {ds_read af pair
// (+bf at ph0) | issue 1 half-stage of t+1 | lgkmcnt+SB | setprio MFMA x16 |
// counted vmcnt at ph1/ph3 | s_barrier}. Half-stage order B0B1,B2B3,A0A2,A1A3
// so ph0 needs only hs0-2 (vmcnt(2) at tile boundary) and A's late halves
// (hs3) arrive one phase before ph2 uses them (vmcnt(4) at ph1). Never a
// mid-loop vmcnt(0) drain (T3+T4). Swizzle: granule ^= row&7 both sides.
template <typename OutT>
__global__ __launch_bounds__(512) void k_gemm8(const bf16* __restrict__ A,
                                               const bf16* __restrict__ Bt,
                                               const float* __restrict__ bias,
                                               OutT* __restrict__ C,
                                               int K, int N, int mblocks) {
  __shared__ bf16 As[2][256 * 64];
  __shared__ bf16 Bs[2][256 * 64];
  const int tid = threadIdx.x;
  const int l = tid & 63, g = l >> 4, c = l & 15;
  const int w = tid >> 6, wr = w >> 2, wc = w & 3;
  // XCD-chunked remap (gridDim.x % 8 == 0)
  int lin = blockIdx.x;
  int nl = (lin & 7) * (gridDim.x >> 3) + (lin >> 3);
  const int row0 = (nl % mblocks) * 256, col0 = (nl / mblocks) * 256;

  const int rr = tid >> 3, jg = tid & 7;
  const int jj = jg ^ (rr & 7);          // source-granule pre-swizzle

  // half-stage p of K-tile kt into buf: 2 x gload16 per thread.
  // p=0: B rows 0-127; p=1: B rows 128-255; p=2: A rows 0-63 & 128-191;
  // p=3: A rows 64-127 & 192-255.
  auto stage_hs = [&](int buf, int kt, int p) {
    if (p < 2) {
      int r0 = p * 128 + rr, r1 = p * 128 + 64 + rr;
      gload16(Bt + (size_t)(col0 + r0) * K + kt * 64 + jj * 8, &Bs[buf][r0 * 64 + jg * 8]);
      gload16(Bt + (size_t)(col0 + r1) * K + kt * 64 + jj * 8, &Bs[buf][r1 * 64 + jg * 8]);
    } else {
      int r0 = (p - 2) * 64 + rr, r1 = 128 + (p - 2) * 64 + rr;
      gload16(A + (size_t)(row0 + r0) * K + kt * 64 + jj * 8, &As[buf][r0 * 64 + jg * 8]);
      gload16(A + (size_t)(row0 + r1) * K + kt * 64 + jj * 8, &As[buf][r1 * 64 + jg * 8]);
    }
  };

  f32x4 acc[8][4] = {};
  bf16x8 bfr[4][2];
  const int NT = K >> 6;

  // prologue: all 4 half-stages of tile 0; wait hs0-2; barrier.
#pragma unroll
  for (int p = 0; p < 4; ++p) stage_hs(0, 0, p);
  asm volatile("s_waitcnt vmcnt(2)" ::: "memory");
  __builtin_amdgcn_sched_barrier(0);
  __builtin_amdgcn_s_barrier();

#pragma unroll 1
  for (int t = 0; t < NT; ++t) {
    const int cur = t & 1;
    const bool nxt = (t + 1 < NT);
    bf16* Asc = &As[cur][0];
    bf16* Bsc = &Bs[cur][0];

    // ---------------- phase 0: m-frags 0,1 + all bf ----------------
    {
#pragma unroll
      for (int n = 0; n < 4; ++n) {
        int row = wc * 64 + n * 16 + c;
#pragma unroll
        for (int kk = 0; kk < 2; ++kk)
          bfr[n][kk] = *(const bf16x8*)&Bsc[row * 64 + ((kk * 4 + g) ^ (c & 7)) * 8];
      }
      bf16x8 af[2][2];
#pragma unroll
      for (int i = 0; i < 2; ++i) {
        int row = wr * 128 + i * 16 + c;
#pragma unroll
        for (int kk = 0; kk < 2; ++kk)
          af[i][kk] = *(const bf16x8*)&Asc[row * 64 + ((kk * 4 + g) ^ (c & 7)) * 8];
      }
      if (nxt) stage_hs(cur ^ 1, t + 1, 0);
      asm volatile("s_waitcnt lgkmcnt(0)" ::: "memory");
      __builtin_amdgcn_sched_barrier(0);
      __builtin_amdgcn_s_setprio(1);
#pragma unroll
      for (int i = 0; i < 2; ++i)
#pragma unroll
        for (int n = 0; n < 4; ++n)
#pragma unroll
          for (int kk = 0; kk < 2; ++kk)
            acc[i][n] = __builtin_amdgcn_mfma_f32_16x16x32_bf16(af[i][kk], bfr[n][kk], acc[i][n], 0, 0, 0);
      __builtin_amdgcn_s_setprio(0);
      __builtin_amdgcn_s_barrier();
    }
    // ---------------- phases 1..3: m-frags 2p,2p+1 ----------------
#pragma unroll
    for (int p = 1; p < 4; ++p) {
      bf16x8 af[2][2];
#pragma unroll
      for (int i = 0; i < 2; ++i) {
        int row = wr * 128 + (2 * p + i) * 16 + c;
#pragma unroll
        for (int kk = 0; kk < 2; ++kk)
          af[i][kk] = *(const bf16x8*)&Asc[row * 64 + ((kk * 4 + g) ^ (c & 7)) * 8];
      }
      if (nxt) stage_hs(cur ^ 1, t + 1, p);
      asm volatile("s_waitcnt lgkmcnt(0)" ::: "memory");
      __builtin_amdgcn_sched_barrier(0);
      __builtin_amdgcn_s_setprio(1);
#pragma unroll
      for (int i = 0; i < 2; ++i)
#pragma unroll
        for (int n = 0; n < 4; ++n)
#pragma unroll
          for (int kk = 0; kk < 2; ++kk)
            acc[2 * p + i][n] = __builtin_amdgcn_mfma_f32_16x16x32_bf16(af[i][kk], bfr[n][kk], acc[2 * p + i][n], 0, 0, 0);
      __builtin_amdgcn_s_setprio(0);
      // counted waits: ph1 -> hs3(t) landed (A1,A3 for ph2/3);
      // ph3 -> hs0-2(t+1) landed (B + A0,A2 for next ph0).
      if (p == 1) {
        if (nxt) { asm volatile("s_waitcnt vmcnt(4)" ::: "memory"); }
        else     { asm volatile("s_waitcnt vmcnt(0)" ::: "memory"); }
        __builtin_amdgcn_sched_barrier(0);
      } else if (p == 3) {
        if (nxt) { asm volatile("s_waitcnt vmcnt(2)" ::: "memory"); }
        __builtin_amdgcn_sched_barrier(0);
      }
      __builtin_amdgcn_s_barrier();
    }
  }

  // ---------------- epilogue ----------------
#pragma unroll
  for (int mi = 0; mi < 8; ++mi) {
    int row = row0 + wr * 128 + mi * 16 + g * 4;
#pragma unroll
    for (int n = 0; n < 4; ++n) {
      int col = col0 + wc * 64 + n * 16 + c;
      float bv = bias[col];
#pragma unroll
      for (int r = 0; r < 4; ++r)
        C[(size_t)(row + r) * N + col] = (OutT)(acc[mi][n][r] + bv);
    }
  }
}

// ---------------- flash attention v7: compacted K/V -----------------------
__global__ __launch_bounds__(256, 4) void k_attn(const bf16* __restrict__ qkv,
                                                 const bf16* __restrict__ kc,
                                                 const bf16* __restrict__ vc,
                                                 bf16* __restrict__ att) {
  const int idx = blockIdx.x;
  const int slot = idx >> 8, j = idx & 255;
  const int r8 = j >> 5, bh = j & 31;
  const int b = bh >> 4, h = bh & 15;
  int qt;
  switch (slot) {
    case 0: qt = r8;       break;
    case 1: qt = 31 - r8;  break;
    case 2: qt = r8 + 8;   break;
    default: qt = 23 - r8; break;
  }

  const int tid = threadIdx.x;
  const int w = tid >> 6, l = tid & 63, g = l >> 4, c = l & 15;
  const int qw0 = qt * 64 + w * 16;
  const int qq = qw0 + c;

  const int nt = (keptcnt(qt * 64 + 64) + 63) >> 6;
  const int tmaskw = keptcnt(qw0 + 1) >> 6;

  __shared__ bf16 Ks[2][64 * 64];
  __shared__ bf16 Vs[2][64 * 64];
  __shared__ bf16 Plds[4][16 * 64];

  const bf16* kgc = kc + (size_t)bh * 1408 * 64;
  const bf16* vgc = vc + (size_t)bh * 64 * 1408;

  auto stage = [&](int buf, int t) {
    int s0 = t * 64;
#pragma unroll
    for (int it = 0; it < 2; ++it) {
      int ch = it * 256 + tid;
      int rr = ch >> 3, jj = (ch & 7) ^ (rr & 7);
      gload16(kgc + (size_t)(s0 + rr) * 64 + jj * 8, &Ks[buf][ch * 8]);
      gload16(vgc + (size_t)rr * 1408 + s0 + jj * 8, &Vs[buf][ch * 8]);
    }
  };

  const bf16* qb = qkv + (size_t)(b * 2048 + qq) * 3072 + h * 64 + g * 8;
  bf16x8 qf0 = *(const bf16x8*)qb;
  bf16x8 qf1 = *(const bf16x8*)(qb + 32);
#pragma unroll
  for (int jq = 0; jq < 8; ++jq) {
    qf0[jq] = (bf16)((float)qf0[jq] * 0.125f);
    qf1[jq] = (bf16)((float)qf1[jq] * 0.125f);
  }

  f32x4 o[4] = {};
  float mrow = -1e30f, ell = 0.f;

  stage(0, 0);

  int cur = 0;
#pragma unroll 1
  for (int t = 0; t < nt; ++t) {
    asm volatile("s_waitcnt vmcnt(0)" ::: "memory");
    __builtin_amdgcn_sched_barrier(0);
    __builtin_amdgcn_s_barrier();
    __builtin_amdgcn_sched_barrier(0);

    if (t + 1 < nt) stage(cur ^ 1, t + 1);

    f32x4 ss[4] = {};
#pragma unroll
    for (int st = 0; st < 4; ++st) {
      bf16x8 ka  = *(const bf16x8*)swz(&Ks[cur][0], st * 16 + c, g * 16);
      bf16x8 kb2 = *(const bf16x8*)swz(&Ks[cur][0], st * 16 + c, 64 + g * 16);
      ss[st] = __builtin_amdgcn_mfma_f32_16x16x32_bf16(ka,  qf0, ss[st], 0, 0, 0);
      ss[st] = __builtin_amdgcn_mfma_f32_16x16x32_bf16(kb2, qf1, ss[st], 0, 0, 0);
    }

    float mloc = -1e30f;
    if (t >= tmaskw) {
#pragma unroll
      for (int st = 0; st < 4; ++st)
#pragma unroll
        for (int r = 0; r < 4; ++r) {
          int ci = t * 64 + st * 16 + g * 4 + r;
          int s = ci2s(ci);
          if (t == 0) s = (ci < 2) ? ci : s;
          float v = (s <= qq) ? ss[st][r] : -1e30f;
          ss[st][r] = v;
          mloc = fmaxf(mloc, v);
        }
    } else {
#pragma unroll
      for (int st = 0; st < 4; ++st)
#pragma unroll
        for (int r = 0; r < 4; ++r) mloc = fmaxf(mloc, ss[st][r]);
    }
    mloc = fmaxf(mloc, __shfl_xor(mloc, 16));
    mloc = fmaxf(mloc, __shfl_xor(mloc, 32));

    float mn = fmaxf(mrow, mloc);
    float al = __expf(mrow - mn);
    mrow = mn;
    float rsum = 0.f;
#pragma unroll
    for (int st = 0; st < 4; ++st) {
      float p0 = __expf(ss[st][0] - mn);
      float p1 = __expf(ss[st][1] - mn);
      float p2 = __expf(ss[st][2] - mn);
      float p3 = __expf(ss[st][3] - mn);
      rsum += (p0 + p1) + (p2 + p3);
      bf16x4 pk = {(bf16)p0, (bf16)p1, (bf16)p2, (bf16)p3};
      *(bf16x4*)swz(&Plds[w][0], c, st * 32 + g * 8) = pk;
    }
    rsum += __shfl_xor(rsum, 16);
    rsum += __shfl_xor(rsum, 32);
    ell = ell * al + rsum;
#pragma unroll
    for (int dc = 0; dc < 4; ++dc)
#pragma unroll
      for (int r = 0; r < 4; ++r) o[dc][r] *= al;

    asm volatile("s_waitcnt lgkmcnt(0)" ::: "memory");
    __builtin_amdgcn_sched_barrier(0);

#pragma unroll
    for (int kk = 0; kk < 2; ++kk) {
      bf16x8 pf = *(const bf16x8*)swz(&Plds[w][0], c, kk * 64 + g * 16);
#pragma unroll
      for (int dc = 0; dc < 4; ++dc) {
        bf16x8 vf = *(const bf16x8*)swz(&Vs[cur][0], dc * 16 + c, kk * 64 + g * 16);
        o[dc] = __builtin_amdgcn_mfma_f32_16x16x32_bf16(vf, pf, o[dc], 0, 0, 0);
      }
    }

    cur ^= 1;
  }

  float inv = 1.f / ell;
#pragma unroll
  for (int dc = 0; dc < 4; ++dc) {
    bf16x4 ok4 = {(bf16)(o[dc][0] * inv), (bf16)(o[dc][1] * inv),
                  (bf16)(o[dc][2] * inv), (bf16)(o[dc][3] * inv)};
    *(bf16x4*)swz(&Plds[w][0], c, dc * 32 + g * 8) = ok4;
  }
  asm volatile("s_waitcnt lgkmcnt(0)" ::: "memory");
  __builtin_amdgcn_sched_barrier(0);
#pragma unroll
  for (int p = 0; p < 2; ++p) {
    int row = p * 8 + (l >> 3);
    bf16x8 vrow = *(const bf16x8*)swz(&Plds[w][0], row, (l & 7) * 16);
    *(bf16x8*)&att[(size_t)(b * 2048 + qt * 64 + w * 16 + row) * 1024 +
                   h * 64 + (l & 7) * 8] = vrow;
  }
}

// ---------------- launcher ----------------
extern "C" void kernel_launch(void* const* d_in, const int* in_sizes, int n_in,
                              void* d_out, int out_size, void* d_ws, size_t ws_size,
                              hipStream_t stream) {
  const float* x  = (const float*)d_in[0];
  const float* Wq = (const float*)d_in[1];
  const float* bq = (const float*)d_in[2];
  const float* Wk = (const float*)d_in[3];
  const float* bk = (const float*)d_in[4];
  const float* Wv = (const float*)d_in[5];
  const float* bv = (const float*)d_in[6];
  const float* Wp = (const float*)d_in[7];
  const float* bp = (const float*)d_in[8];
  float* out = (float*)d_out;

  char* ws = (char*)d_ws;
  const size_t MB = 1024 * 1024;
  bf16*  xb    = (bf16*)(ws);             // 8 MB [4096][1024]; reused as att
  bf16*  wqkvT = (bf16*)(ws + 8 * MB);    // 6 MB; dead after QKV GEMM
  bf16*  wpT   = (bf16*)(ws + 14 * MB);   // 2 MB [1024][1024]
  float* bcat  = (float*)(ws + 16 * MB);  // 12 KB
  bf16*  qkv   = (bf16*)(ws + 17 * MB);   // 24 MB [4096][3072]
  bf16*  kcb   = wqkvT;                   // 5.5 MB [32][1408][64] (over dead wqkvT)
  bf16*  vcb   = (bf16*)(ws + 41 * MB);   // 5.5 MB [32][64][1408]
  bf16*  att   = xb;                      // alias: xb dead after QKV GEMM

  k_cvt_bf16<<<2048, 256, 0, stream>>>(x, xb, 524288);
  k_wt<<<512, 256, 0, stream>>>(Wq, wqkvT);
  k_wt<<<512, 256, 0, stream>>>(Wk, wqkvT + 1024 * 1024);
  k_wt<<<512, 256, 0, stream>>>(Wv, wqkvT + 2 * 1024 * 1024);
  k_wt<<<512, 256, 0, stream>>>(Wp, wpT);
  k_bcat<<<12, 256, 0, stream>>>(bq, bk, bv, bcat);

  // QKV: 256^2 8-phase (M=4096 -> 16 mblocks, N=3072 -> 12 nblocks)
  k_gemm8<bf16><<<192, 512, 0, stream>>>(xb, wqkvT, bcat, qkv, 1024, 3072, 16);
  k_compact_k<<<1408, 256, 0, stream>>>(qkv, kcb);
  k_compact_v<<<704, 256, 0, stream>>>(qkv, vcb);
  k_attn<<<1024, 256, 0, stream>>>(qkv, kcb, vcb, att);
  k_gemm_bt<float><<<dim3(32, 8), 256, 0, stream>>>(att, wpT, bp, out, 1024, 1024);
}